// Round 7
// baseline (202.164 us; speedup 1.0000x reference)
//
#include <hip/hip_runtime.h>
#include <stdint.h>
#include <stddef.h>

// BlockLinear: out[b, g*512+n] = sum_m x[b, g*512+m] * blocks[g, m, n]
// G=8, M=N=512, TOKENS=8192. fp32 in/out; compute in bf16 MFMA.
// Round 7: ABLATION ROUND. template<MODE> probes dispatched before the
// real kernel (MODE 3, runs last, produces correct output):
//   MODE 0: barrier skeleton only
//   MODE 1: staging only  (A loads+cvt+ds_write, B gl_lds; no compute)
//   MODE 2: compute only  (ds_read+MFMA from junk LDS; no global traffic)
//   MODE 3: full (R5 loop structure + R6 conflict-free swizzle)
// Per-dispatch dur_us from rocprof isolates the binding path.

typedef __attribute__((ext_vector_type(8))) short sv8;   // 8 x bf16 fragment
typedef __attribute__((ext_vector_type(4))) float fv4;   // 4 x f32 accum

__device__ __forceinline__ uint32_t f2bf(float f) {
    union { float f; uint32_t u; } v; v.f = f;
    uint32_t u = v.u;
    u += 0x7FFFu + ((u >> 16) & 1u);   // RNE
    return u >> 16;
}
__device__ __forceinline__ uint32_t pk2(float a, float b) {
    return f2bf(a) | (f2bf(b) << 16);
}
__device__ __forceinline__ void gl_lds16(const void* g, void* lds) {
    __builtin_amdgcn_global_load_lds(
        (const __attribute__((address_space(1))) void*)g,
        (__attribute__((address_space(3))) void*)lds, 16, 0, 0);
}

// bTgl[g][kt][n*4+slot] : 16B unit = bf16(blocks[g][kt*32 + c*8 + e][n]),
// e=0..7, c = slot ^ ((n>>1)&3).  8 g x 16 kt x 2048 units x 16B = 4 MiB.
__global__ void bl_pack(const float* __restrict__ blocks,
                        unsigned short* __restrict__ bTgl) {
    __shared__ float tile[64][65];
    const int g  = blockIdx.z;
    const int mt = blockIdx.y;           // 64 m-rows -> kt = mt*2 + {0,1}
    const int n0 = blockIdx.x * 64;
    const float* src = blocks + (size_t)g * 512 * 512;
    const int lane = threadIdx.x & 63;
    const int r0   = threadIdx.x >> 6;   // 0..3
    for (int r = r0; r < 64; r += 4)
        tile[r][lane] = src[(size_t)(mt * 64 + r) * 512 + n0 + lane];
    __syncthreads();
    const int t    = threadIdx.x;        // 0..255
    const int nl   = t >> 2;
    const int slot = t & 3;
    const int c    = slot ^ ((nl >> 1) & 3);   // n0 multiple of 64
#pragma unroll
    for (int ktl = 0; ktl < 2; ++ktl) {
        const int mb = ktl * 32 + c * 8;
        uint4 w;
        w.x = pk2(tile[mb + 0][nl], tile[mb + 1][nl]);
        w.y = pk2(tile[mb + 2][nl], tile[mb + 3][nl]);
        w.z = pk2(tile[mb + 4][nl], tile[mb + 5][nl]);
        w.w = pk2(tile[mb + 6][nl], tile[mb + 7][nl]);
        const size_t u = ((size_t)(g * 16 + mt * 2 + ktl)) * 2048 + (n0 + nl) * 4 + slot;
        *(uint4*)(bTgl + u * 8) = w;
    }
}

// MODE: 0 = barriers only, 1 = staging only, 2 = compute only, 3 = full.
template<int MODE>
__global__ __launch_bounds__(256, 4) void bl_gemm(
    const float* __restrict__ x,              // [8192][4096]
    const unsigned short* __restrict__ bTgl,  // packed B, see bl_pack
    float* __restrict__ out)                  // [8192][4096]
{
    constexpr bool STAGE = (MODE == 1) || (MODE == 3);
    constexpr bool COMP  = (MODE == 2) || (MODE == 3);

    __shared__ __align__(16) unsigned short As[2][64 * 32];    //  8 KiB
    __shared__ __align__(16) unsigned short Bs[2][256 * 32];   // 32 KiB

    const int bid = blockIdx.x;
    const int g   = bid & 7;          // group ~ XCD (round-robin dispatch)
    const int rem = bid >> 3;
    const int nt  = rem & 1;
    const int mt  = rem >> 1;         // 0..127

    const int tid  = threadIdx.x;
    const int lane = tid & 63;
    const int w    = tid >> 6;        // 0..3 = wn
    const int lr   = lane & 15;
    const int lg   = lane >> 4;

    fv4 acc[4][4];
#pragma unroll
    for (int i = 0; i < 4; ++i)
#pragma unroll
        for (int j = 0; j < 4; ++j)
            acc[i][j] = (fv4){0.f, 0.f, 0.f, 0.f};

    const float* xg = x + (size_t)(mt * 64) * 4096 + g * 512;

    // ---- A staging: thread -> row arow (0..63), k-chunk ac (8 floats) ----
    const int arow = tid >> 2;
    const int ac   = tid & 3;
    const float* aSrc = xg + (size_t)arow * 4096 + ac * 8;
    const int aOff = arow * 64 + ((ac ^ ((arow >> 1) & 3)) * 16);  // bytes

    // ---- B staging: 4 gl_lds per wave, fully linear (packed layout) ----
    const unsigned short* bKt0 =
        bTgl + ((size_t)g * 16) * 2048 * 8 + (size_t)nt * 1024 * 8 +
        (size_t)(w * 256 + lane) * 8;

    // ---- fragment read slot (bytes); (row>>1)&3 == (lr>>1)&3 everywhere ----
    const int slotOff = (lg ^ ((lr >> 1) & 3)) * 16;
    const int aReadRow = lr * 64;               // + mi*16*64
    const int bReadRow = (w * 64 + lr) * 64;    // + ni*16*64

    float4 ar0_, ar1_;   // in-flight A (8 floats)

#define ISSUE_A(kt)                                                        \
    do {                                                                   \
        const float* s_ = aSrc + (kt) * 32;                                \
        ar0_ = *(const float4*)s_;                                         \
        ar1_ = *(const float4*)(s_ + 4);                                   \
    } while (0)

#define ISSUE_B(kt, bufw)                                                  \
    do { _Pragma("unroll") for (int p = 0; p < 4; ++p)                     \
        gl_lds16(bKt0 + (size_t)(kt) * 16384 + p * 512,                    \
                 (char*)&Bs[0][0] + (bufw) * 16384 + (w * 256 + p * 64) * 16); \
    } while (0)

#define WRITE_A(bufw)                                                      \
    do {                                                                   \
        uint4 w_;                                                          \
        w_.x = pk2(ar0_.x, ar0_.y); w_.y = pk2(ar0_.z, ar0_.w);            \
        w_.z = pk2(ar1_.x, ar1_.y); w_.w = pk2(ar1_.z, ar1_.w);            \
        *(uint4*)((char*)&As[0][0] + (bufw) * 4096 + aOff) = w_;           \
    } while (0)

#define COMPUTE(rb)                                                        \
    do {                                                                   \
        sv8 a_[4], b_[4];                                                  \
        _Pragma("unroll") for (int mi = 0; mi < 4; ++mi)                   \
            a_[mi] = *(const sv8*)((const char*)&As[0][0] + (rb) * 4096 +  \
                                   aReadRow + mi * 16 * 64 + slotOff);     \
        _Pragma("unroll") for (int ni = 0; ni < 4; ++ni)                   \
            b_[ni] = *(const sv8*)((const char*)&Bs[0][0] + (rb) * 16384 + \
                                   bReadRow + ni * 16 * 64 + slotOff);     \
        __builtin_amdgcn_s_setprio(1);                                     \
        _Pragma("unroll") for (int mi = 0; mi < 4; ++mi)                   \
        _Pragma("unroll") for (int ni = 0; ni < 4; ++ni)                   \
            acc[mi][ni] = __builtin_amdgcn_mfma_f32_16x16x32_bf16(         \
                b_[ni], a_[mi], acc[mi][ni], 0, 0, 0);                     \
        __builtin_amdgcn_s_setprio(0);                                     \
    } while (0)

    // ---- prologue ----
    if constexpr (STAGE) {
        ISSUE_A(0);
        ISSUE_B(0, 0);
        WRITE_A(0);
    }
    __syncthreads();

#pragma unroll 1
    for (int kt = 0; kt < 16; kt += 2) {
        if constexpr (STAGE) { ISSUE_A(kt + 1); ISSUE_B(kt + 1, 1); }
        if constexpr (COMP)  COMPUTE(0);
        if constexpr (STAGE) WRITE_A(1);
        __syncthreads();
        if constexpr (STAGE) if (kt + 2 < 16) { ISSUE_A(kt + 2); ISSUE_B(kt + 2, 0); }
        if constexpr (COMP)  COMPUTE(1);
        if constexpr (STAGE) if (kt + 2 < 16) WRITE_A(0);
        __syncthreads();
    }

    // ---- epilogue: nontemporal float4 stores (lane holds 4 consecutive n)
    float* og = out + (size_t)(mt * 64) * 4096 + g * 512 + nt * 256 + w * 64;
#pragma unroll
    for (int mi = 0; mi < 4; ++mi)
#pragma unroll
        for (int ni = 0; ni < 4; ++ni)
            __builtin_nontemporal_store(
                acc[mi][ni],
                (fv4*)(og + (size_t)(mi * 16 + lr) * 4096 + ni * 16 + lg * 4));

#undef ISSUE_A
#undef ISSUE_B
#undef WRITE_A
#undef COMPUTE
}

// Safety net if ws is too small for the packed bf16 blocks (4 MiB).
__global__ void bl_fallback(const float* __restrict__ x,
                            const float* __restrict__ blocks,
                            float* __restrict__ out) {
    const int o = blockIdx.x * 256 + threadIdx.x;
    const int col = o & 4095;
    const int row = o >> 12;
    const int g = col >> 9;
    const int n = col & 511;
    const float* xr = x + (size_t)row * 4096 + g * 512;
    const float* wp = blocks + (size_t)g * 512 * 512 + n;
    float s = 0.f;
    for (int m = 0; m < 512; ++m) s += xr[m] * wp[(size_t)m * 512];
    out[o] = s;
}

extern "C" void kernel_launch(void* const* d_in, const int* in_sizes, int n_in,
                              void* d_out, int out_size, void* d_ws, size_t ws_size,
                              hipStream_t stream) {
    const float* x      = (const float*)d_in[0];
    const float* blocks = (const float*)d_in[1];
    float* out          = (float*)d_out;

    const size_t need = (size_t)8 * 16 * 2048 * 16;   // 4 MiB packed B
    if (ws_size >= need) {
        unsigned short* bTgl = (unsigned short*)d_ws;
        bl_pack<<<dim3(8, 8, 8), 256, 0, stream>>>(blocks, bTgl);
        // ---- ablation probes (junk results into d_out; overwritten below)
        bl_gemm<0><<<2048, 256, 0, stream>>>(x, bTgl, out);  // barriers only
        bl_gemm<1><<<2048, 256, 0, stream>>>(x, bTgl, out);  // staging only
        bl_gemm<2><<<2048, 256, 0, stream>>>(x, bTgl, out);  // compute only
        // ---- real kernel (runs last, produces the validated output)
        bl_gemm<3><<<2048, 256, 0, stream>>>(x, bTgl, out);
    } else {
        bl_fallback<<<(8192 * 4096) / 256, 256, 0, stream>>>(x, blocks, out);
    }
}

// Round 8
// 78.030 us; speedup vs baseline: 2.5908x; 2.5908x over previous
//
#include <hip/hip_runtime.h>
#include <stdint.h>
#include <stddef.h>

// BlockLinear: out[b, g*512+n] = sum_m x[b, g*512+m] * blocks[g, m, n]
// G=8, M=N=512, TOKENS=8192. fp32 in/out; compute in bf16 MFMA.
// Round 8: staging-dominated (R7 ablation) -> read x ONCE (BN=512),
// 8-wave blocks BM=64 BN=512 BK=32, 72KB LDS -> 2 blocks/CU,
// 2-deep A-register prefetch. Simple dbuf + __syncthreads (R5/R6 showed
// counted-vmcnt neutral here).

typedef __attribute__((ext_vector_type(8))) short sv8;   // 8 x bf16 fragment
typedef __attribute__((ext_vector_type(4))) float fv4;   // 4 x f32 accum

__device__ __forceinline__ uint32_t f2bf(float f) {
    union { float f; uint32_t u; } v; v.f = f;
    uint32_t u = v.u;
    u += 0x7FFFu + ((u >> 16) & 1u);   // RNE
    return u >> 16;
}
__device__ __forceinline__ uint32_t pk2(float a, float b) {
    return f2bf(a) | (f2bf(b) << 16);
}
__device__ __forceinline__ void gl_lds16(const void* g, void* lds) {
    __builtin_amdgcn_global_load_lds(
        (const __attribute__((address_space(1))) void*)g,
        (__attribute__((address_space(3))) void*)lds, 16, 0, 0);
}

// bTgl[g][kt][n*4+slot] : 16B unit = bf16(blocks[g][kt*32 + c*8 + e][n]),
// e=0..7, c = slot ^ ((n>>1)&3).  8 g x 16 kt x 2048 units x 16B = 4 MiB.
__global__ void bl_pack(const float* __restrict__ blocks,
                        unsigned short* __restrict__ bTgl) {
    __shared__ float tile[64][65];
    const int g  = blockIdx.z;
    const int mt = blockIdx.y;           // 64 m-rows -> kt = mt*2 + {0,1}
    const int n0 = blockIdx.x * 64;
    const float* src = blocks + (size_t)g * 512 * 512;
    const int lane = threadIdx.x & 63;
    const int r0   = threadIdx.x >> 6;   // 0..3
    for (int r = r0; r < 64; r += 4)
        tile[r][lane] = src[(size_t)(mt * 64 + r) * 512 + n0 + lane];
    __syncthreads();
    const int t    = threadIdx.x;        // 0..255
    const int nl   = t >> 2;
    const int slot = t & 3;
    const int c    = slot ^ ((nl >> 1) & 3);   // n0 multiple of 64
#pragma unroll
    for (int ktl = 0; ktl < 2; ++ktl) {
        const int mb = ktl * 32 + c * 8;
        uint4 w;
        w.x = pk2(tile[mb + 0][nl], tile[mb + 1][nl]);
        w.y = pk2(tile[mb + 2][nl], tile[mb + 3][nl]);
        w.z = pk2(tile[mb + 4][nl], tile[mb + 5][nl]);
        w.w = pk2(tile[mb + 6][nl], tile[mb + 7][nl]);
        const size_t u = ((size_t)(g * 16 + mt * 2 + ktl)) * 2048 + (n0 + nl) * 4 + slot;
        *(uint4*)(bTgl + u * 8) = w;
    }
}

// Main GEMM: BM=64, BN=512, BK=32, 512 threads (8 waves, 1Mx8N),
// wave tile 64x64 = 4x4 fragments of 16x16x32 bf16 MFMA.
// LDS 72 KiB (A 2x4K, B 2x32K) -> 2 blocks/CU. x read exactly once.
__global__ __launch_bounds__(512, 4) void bl_gemm(
    const float* __restrict__ x,              // [8192][4096]
    const unsigned short* __restrict__ bTgl,  // packed B, see bl_pack
    float* __restrict__ out)                  // [8192][4096]
{
    __shared__ __align__(16) unsigned short As[2][64 * 32];    //  8 KiB
    __shared__ __align__(16) unsigned short Bs[2][512 * 32];   // 64 KiB

    const int bid = blockIdx.x;
    const int g   = bid & 7;          // group ~ XCD (round-robin dispatch)
    const int mt  = bid >> 3;         // 0..127

    const int tid  = threadIdx.x;
    const int lane = tid & 63;
    const int w    = tid >> 6;        // 0..7 = wn
    const int lr   = lane & 15;
    const int lg   = lane >> 4;

    fv4 acc[4][4];
#pragma unroll
    for (int i = 0; i < 4; ++i)
#pragma unroll
        for (int j = 0; j < 4; ++j)
            acc[i][j] = (fv4){0.f, 0.f, 0.f, 0.f};

    const float* xg = x + (size_t)(mt * 64) * 4096 + g * 512;

    // ---- A staging: thread -> row arow (0..63), 4-float chunk ac (0..7) ----
    const int arow = tid >> 3;
    const int ac   = tid & 3 + 0;     // placeholder; real below
    const int ac8  = tid & 7;         // 8B chunk index within 64B row
    const float* aSrc = xg + (size_t)arow * 4096 + ac8 * 4;
    // byte offset: 16B slot s=ac8>>1 swizzled, half=ac8&1
    const int aOff = arow * 64 + (((ac8 >> 1) ^ ((arow >> 1) & 3)) * 16) + (ac8 & 1) * 8;
    (void)ac;

    // ---- B staging: 4 gl_lds per wave, fully linear (packed layout) ----
    const unsigned short* bKt0 =
        bTgl + ((size_t)g * 16) * 2048 * 8 + (size_t)(w * 256 + lane) * 8;

    // ---- fragment read slot (bytes); (row>>1)&3 == (lr>>1)&3 everywhere ----
    const int slotOff = (lg ^ ((lr >> 1) & 3)) * 16;
    const int aReadRow = lr * 64;               // + mi*16*64
    const int bReadRow = (w * 64 + lr) * 64;    // + ni*16*64

    float4 arP_, arQ_;   // 2-deep in-flight A (4 floats each)

#define ISSUE_A(kt, dst)                                                   \
    do { (dst) = *(const float4*)(aSrc + (kt) * 32); } while (0)

#define ISSUE_B(kt, bufw)                                                  \
    do { _Pragma("unroll") for (int p = 0; p < 4; ++p)                     \
        gl_lds16(bKt0 + (size_t)(kt) * 16384 + p * 512,                    \
                 (char*)&Bs[0][0] + (bufw) * 32768 + (w * 256 + p * 64) * 16); \
    } while (0)

#define WRITE_A(bufw, src)                                                 \
    do {                                                                   \
        uint2 w_;                                                          \
        w_.x = pk2((src).x, (src).y); w_.y = pk2((src).z, (src).w);        \
        *(uint2*)((char*)&As[0][0] + (bufw) * 4096 + aOff) = w_;           \
    } while (0)

#define COMPUTE(rb)                                                        \
    do {                                                                   \
        sv8 a_[4], b_[4];                                                  \
        _Pragma("unroll") for (int mi = 0; mi < 4; ++mi)                   \
            a_[mi] = *(const sv8*)((const char*)&As[0][0] + (rb) * 4096 +  \
                                   aReadRow + mi * 16 * 64 + slotOff);     \
        _Pragma("unroll") for (int ni = 0; ni < 4; ++ni)                   \
            b_[ni] = *(const sv8*)((const char*)&Bs[0][0] + (rb) * 32768 + \
                                   bReadRow + ni * 16 * 64 + slotOff);     \
        __builtin_amdgcn_s_setprio(1);                                     \
        _Pragma("unroll") for (int mi = 0; mi < 4; ++mi)                   \
        _Pragma("unroll") for (int ni = 0; ni < 4; ++ni)                   \
            acc[mi][ni] = __builtin_amdgcn_mfma_f32_16x16x32_bf16(         \
                b_[ni], a_[mi], acc[mi][ni], 0, 0, 0);                     \
        __builtin_amdgcn_s_setprio(0);                                     \
    } while (0)

    // ---- prologue: tile 0 staged into buf 0; A(1) in flight ----
    ISSUE_A(0, arP_);
    ISSUE_B(0, 0);
    WRITE_A(0, arP_);
    ISSUE_A(1, arP_);
    __syncthreads();

    // invariant at loop top: buf0 ready for tile kt, arP_ = A(kt+1)
#pragma unroll 1
    for (int kt = 0; kt < 16; kt += 2) {
        const int ka = kt + 2 < 16 ? kt + 2 : 15;
        const int kb = kt + 3 < 16 ? kt + 3 : 15;
        // tile kt (buf0)
        ISSUE_A(ka, arQ_);             // A(kt+2), 2 phases ahead
        ISSUE_B(kt + 1, 1);
        COMPUTE(0);
        WRITE_A(1, arP_);              // A(kt+1) -> buf1
        __syncthreads();
        // tile kt+1 (buf1)
        ISSUE_A(kb, arP_);             // A(kt+3)
        ISSUE_B(ka, 0);
        COMPUTE(1);
        WRITE_A(0, arQ_);              // A(kt+2) -> buf0
        __syncthreads();
    }

    // ---- epilogue: nontemporal float4 stores (lane holds 4 consecutive n)
    float* og = out + (size_t)(mt * 64) * 4096 + g * 512 + w * 64;
#pragma unroll
    for (int mi = 0; mi < 4; ++mi)
#pragma unroll
        for (int ni = 0; ni < 4; ++ni)
            __builtin_nontemporal_store(
                acc[mi][ni],
                (fv4*)(og + (size_t)(mi * 16 + lr) * 4096 + ni * 16 + lg * 4));

#undef ISSUE_A
#undef ISSUE_B
#undef WRITE_A
#undef COMPUTE
}

// Safety net if ws is too small for the packed bf16 blocks (4 MiB).
__global__ void bl_fallback(const float* __restrict__ x,
                            const float* __restrict__ blocks,
                            float* __restrict__ out) {
    const int o = blockIdx.x * 256 + threadIdx.x;
    const int col = o & 4095;
    const int row = o >> 12;
    const int g = col >> 9;
    const int n = col & 511;
    const float* xr = x + (size_t)row * 4096 + g * 512;
    const float* wp = blocks + (size_t)g * 512 * 512 + n;
    float s = 0.f;
    for (int m = 0; m < 512; ++m) s += xr[m] * wp[(size_t)m * 512];
    out[o] = s;
}

extern "C" void kernel_launch(void* const* d_in, const int* in_sizes, int n_in,
                              void* d_out, int out_size, void* d_ws, size_t ws_size,
                              hipStream_t stream) {
    const float* x      = (const float*)d_in[0];
    const float* blocks = (const float*)d_in[1];
    float* out          = (float*)d_out;

    const size_t need = (size_t)8 * 16 * 2048 * 16;   // 4 MiB packed B
    if (ws_size >= need) {
        unsigned short* bTgl = (unsigned short*)d_ws;
        bl_pack<<<dim3(8, 8, 8), 256, 0, stream>>>(blocks, bTgl);
        bl_gemm<<<1024, 512, 0, stream>>>(x, bTgl, out);
    } else {
        bl_fallback<<<(8192 * 4096) / 256, 256, 0, stream>>>(x, blocks, out);
    }
}

// Round 9
// 71.926 us; speedup vs baseline: 2.8107x; 1.0849x over previous
//
#include <hip/hip_runtime.h>
#include <stdint.h>
#include <stddef.h>

// BlockLinear: out[b, g*512+n] = sum_m x[b, g*512+m] * blocks[g, m, n]
// G=8, M=N=512, TOKENS=8192. fp32 in/out; compute in bf16 MFMA.
// Round 9: B never touches LDS — packed bTgl units ARE the MFMA fragments,
// per-wave register-prefetched straight from L2 (1 KB coalesced per load).
// A-only LDS (8 KB dbuf). 4-wave blocks, BM=64 BN=256 BK=32, 16 waves/CU.

typedef __attribute__((ext_vector_type(8))) short sv8;   // 8 x bf16 fragment
typedef __attribute__((ext_vector_type(4))) float fv4;   // 4 x f32 accum

__device__ __forceinline__ uint32_t f2bf(float f) {
    union { float f; uint32_t u; } v; v.f = f;
    uint32_t u = v.u;
    u += 0x7FFFu + ((u >> 16) & 1u);   // RNE
    return u >> 16;
}
__device__ __forceinline__ uint32_t pk2(float a, float b) {
    return f2bf(a) | (f2bf(b) << 16);
}

#define BAR()   __builtin_amdgcn_s_barrier()
#define SB0()   __builtin_amdgcn_sched_barrier(0)
#define LGKM0() do { asm volatile("s_waitcnt lgkmcnt(0)" ::: "memory"); SB0(); } while (0)

// bTgl[g][kt] : 2048 units of 16B; unit u = n*4 + c holds
// bf16(blocks[g][kt*32 + c*8 + e][n]), e=0..7.  (fragment-ready layout)
__global__ void bl_pack(const float* __restrict__ blocks,
                        unsigned short* __restrict__ bTgl) {
    __shared__ float tile[64][65];
    const int g  = blockIdx.z;
    const int mt = blockIdx.y;           // 64 m-rows -> kt = mt*2 + {0,1}
    const int n0 = blockIdx.x * 64;
    const float* src = blocks + (size_t)g * 512 * 512;
    const int lane = threadIdx.x & 63;
    const int r0   = threadIdx.x >> 6;   // 0..3
    for (int r = r0; r < 64; r += 4)
        tile[r][lane] = src[(size_t)(mt * 64 + r) * 512 + n0 + lane];
    __syncthreads();
    const int t    = threadIdx.x;        // 0..255
    const int nl   = t >> 2;
    const int c    = t & 3;              // k-chunk == slot (no swizzle)
#pragma unroll
    for (int ktl = 0; ktl < 2; ++ktl) {
        const int mb = ktl * 32 + c * 8;
        uint4 w;
        w.x = pk2(tile[mb + 0][nl], tile[mb + 1][nl]);
        w.y = pk2(tile[mb + 2][nl], tile[mb + 3][nl]);
        w.z = pk2(tile[mb + 4][nl], tile[mb + 5][nl]);
        w.w = pk2(tile[mb + 6][nl], tile[mb + 7][nl]);
        const size_t u = ((size_t)(g * 16 + mt * 2 + ktl)) * 2048 + (n0 + nl) * 4 + c;
        *(uint4*)(bTgl + u * 8) = w;
    }
}

// Main GEMM: BM=64, BN=256, BK=32, 256 threads (4 waves, 1Mx4N),
// wave tile 64x64 = 4x4 fragments of 16x16x32 bf16 MFMA.
// A: LDS dbuf (8 KiB), swizzled, shared by 4 waves. B: register prefetch
// direct from packed global (no LDS, no barrier coupling).
__global__ __launch_bounds__(256, 4) void bl_gemm(
    const float* __restrict__ x,              // [8192][4096]
    const unsigned short* __restrict__ bTgl,  // packed B, see bl_pack
    float* __restrict__ out)                  // [8192][4096]
{
    __shared__ __align__(16) unsigned short As[2][64 * 32];    // 8 KiB

    const int bid = blockIdx.x;
    const int g   = bid & 7;          // group ~ XCD (round-robin dispatch)
    const int rem = bid >> 3;
    const int nt  = rem & 1;
    const int mt  = rem >> 1;         // 0..127

    const int tid  = threadIdx.x;
    const int lane = tid & 63;
    const int w    = tid >> 6;        // 0..3 = wn
    const int lr   = lane & 15;
    const int lg   = lane >> 4;

    fv4 acc[4][4];
#pragma unroll
    for (int i = 0; i < 4; ++i)
#pragma unroll
        for (int j = 0; j < 4; ++j)
            acc[i][j] = (fv4){0.f, 0.f, 0.f, 0.f};

    const float* xg = x + (size_t)(mt * 64) * 4096 + g * 512;

    // ---- A staging: thread -> row arow (0..63), 8-float chunk ac (0..3) ----
    const int arow = tid >> 2;
    const int ac   = tid & 3;
    const float* aSrc = xg + (size_t)arow * 4096 + ac * 8;
    const int aOff = arow * 64 + ((ac ^ ((arow >> 1) & 3)) * 16);  // bytes

    // ---- B fragments: lane-direct from packed layout ----
    // unit u = n*4 + lg, n = nt*256 + w*64 + ni*16 + lr; elems = u*8
    const unsigned short* bLane =
        bTgl + ((size_t)(g * 16) * 2048 +
                (size_t)(nt * 256 + w * 64 + lr) * 4 + lg) * 8;

    // ---- A fragment read slot (bytes) ----
    const int slotOff = (lg ^ ((lr >> 1) & 3)) * 16;

    float4 a0_, a1_;       // in-flight A (8 floats)
    sv8 bP[4], bQ[4];      // B fragments: current / next tile

#define ISSUE_A(kt)                                                        \
    do {                                                                   \
        const float* s_ = aSrc + (kt) * 32;                                \
        a0_ = *(const float4*)s_;                                          \
        a1_ = *(const float4*)(s_ + 4);                                    \
    } while (0)

#define ISSUE_BF(kt, dst)                                                  \
    do { _Pragma("unroll") for (int ni = 0; ni < 4; ++ni)                  \
        dst[ni] = *(const sv8*)(bLane + (size_t)(kt) * 16384 + ni * 512);  \
    } while (0)

#define WRITE_A(bufw)                                                      \
    do {                                                                   \
        uint4 w_;                                                          \
        w_.x = pk2(a0_.x, a0_.y); w_.y = pk2(a0_.z, a0_.w);                \
        w_.z = pk2(a1_.x, a1_.y); w_.w = pk2(a1_.z, a1_.w);                \
        *(uint4*)((char*)&As[0][0] + (bufw) * 4096 + aOff) = w_;           \
    } while (0)

#define COMPUTE(rb, breg)                                                  \
    do {                                                                   \
        sv8 a_[4];                                                         \
        _Pragma("unroll") for (int mi = 0; mi < 4; ++mi)                   \
            a_[mi] = *(const sv8*)((const char*)&As[0][0] + (rb) * 4096 +  \
                                   (mi * 16 + lr) * 64 + slotOff);         \
        __builtin_amdgcn_s_setprio(1);                                     \
        _Pragma("unroll") for (int mi = 0; mi < 4; ++mi)                   \
        _Pragma("unroll") for (int ni = 0; ni < 4; ++ni)                   \
            acc[mi][ni] = __builtin_amdgcn_mfma_f32_16x16x32_bf16(         \
                breg[ni], a_[mi], acc[mi][ni], 0, 0, 0);                   \
        __builtin_amdgcn_s_setprio(0);                                     \
    } while (0)

    // ---- prologue: tile 0 -> buf0 + bP ----
    ISSUE_BF(0, bP);
    ISSUE_A(0);
    WRITE_A(0);
    LGKM0();
    BAR();

#pragma unroll 1
    for (int kt = 0; kt < 16; kt += 2) {
        const int ka = kt + 1 < 16 ? kt + 1 : 15;
        const int kb = kt + 2 < 16 ? kt + 2 : 15;
        // phase A: tile kt (buf0, bP); stage kt+1
        ISSUE_BF(ka, bQ);
        ISSUE_A(ka);
        COMPUTE(0, bP);
        WRITE_A(1);
        LGKM0();
        BAR();
        // phase B: tile kt+1 (buf1, bQ); stage kt+2
        ISSUE_BF(kb, bP);
        ISSUE_A(kb);
        COMPUTE(1, bQ);
        WRITE_A(0);
        LGKM0();
        BAR();
    }

    // ---- epilogue: nontemporal float4 stores (lane holds 4 consecutive n)
    float* og = out + (size_t)(mt * 64) * 4096 + g * 512 + nt * 256 + w * 64;
#pragma unroll
    for (int mi = 0; mi < 4; ++mi)
#pragma unroll
        for (int ni = 0; ni < 4; ++ni)
            __builtin_nontemporal_store(
                acc[mi][ni],
                (fv4*)(og + (size_t)(mi * 16 + lr) * 4096 + ni * 16 + lg * 4));

#undef ISSUE_A
#undef ISSUE_BF
#undef WRITE_A
#undef COMPUTE
}

// Safety net if ws is too small for the packed bf16 blocks (4 MiB).
__global__ void bl_fallback(const float* __restrict__ x,
                            const float* __restrict__ blocks,
                            float* __restrict__ out) {
    const int o = blockIdx.x * 256 + threadIdx.x;
    const int col = o & 4095;
    const int row = o >> 12;
    const int g = col >> 9;
    const int n = col & 511;
    const float* xr = x + (size_t)row * 4096 + g * 512;
    const float* wp = blocks + (size_t)g * 512 * 512 + n;
    float s = 0.f;
    for (int m = 0; m < 512; ++m) s += xr[m] * wp[(size_t)m * 512];
    out[o] = s;
}

extern "C" void kernel_launch(void* const* d_in, const int* in_sizes, int n_in,
                              void* d_out, int out_size, void* d_ws, size_t ws_size,
                              hipStream_t stream) {
    const float* x      = (const float*)d_in[0];
    const float* blocks = (const float*)d_in[1];
    float* out          = (float*)d_out;

    const size_t need = (size_t)8 * 16 * 2048 * 16;   // 4 MiB packed B
    if (ws_size >= need) {
        unsigned short* bTgl = (unsigned short*)d_ws;
        bl_pack<<<dim3(8, 8, 8), 256, 0, stream>>>(blocks, bTgl);
        bl_gemm<<<2048, 256, 0, stream>>>(x, bTgl, out);
    } else {
        bl_fallback<<<(8192 * 4096) / 256, 256, 0, stream>>>(x, blocks, out);
    }
}